// Round 7
// baseline (278.930 us; speedup 1.0000x reference)
//
#include <hip/hip_runtime.h>
#include <hip/hip_bf16.h>

typedef unsigned short u16;
typedef unsigned int u32;

constexpr int kHW  = 16384;   // 128*128
constexpr int kC   = 192;
constexpr int kC3  = 576;
constexpr int kHD  = 48;
constexpr int kB   = 8;
constexpr int kSCH = 16;      // S-partial chunks (1024 n each)

typedef __attribute__((ext_vector_type(8))) short bfx8;  // 8 bf16 in 4 VGPRs
typedef __attribute__((ext_vector_type(4))) float fx4;

__device__ __forceinline__ float bfu2f(u32 u) { return __uint_as_float(u << 16); }
__device__ __forceinline__ u16 f2bfu(float f) {
  u32 x = __float_as_uint(f);
  return (u16)((x + 0x7fffu + ((x >> 16) & 1u)) >> 16);  // RNE
}
__device__ __forceinline__ u32 pack2(float a, float b) {
  union { __hip_bfloat162 h; u32 u; } cv;
  cv.h = __float22bfloat162_rn(make_float2(a, b));  // v_cvt_pk_bf16_f32
  return cv.u;
}

// ---------------------------------------------------------------------------
// P1: f32 -> bf16 cast (for w_qkv)
// ---------------------------------------------------------------------------
__global__ __launch_bounds__(256) void cast_f32_bf16(
    const float* __restrict__ in, u16* __restrict__ out, int n) {
  int i = blockIdx.x * 256 + threadIdx.x;
  if (i < n) out[i] = f2bfu(in[i]);
}

// ---------------------------------------------------------------------------
// K1/K5: MFMA GEMM, B consumed DIRECTLY from [k][n] row-major global layout.
// Out[b][o][n] = sum_k A[b?][o][k] * B[b][k][n], K = 192.
// Block 64o x 256n, 4 waves. The k<->n transpose lives in the LDS layout:
// B element (k,n) stored at u32 word (k/2)*260 + n, half (k&1)
// ("k-pair interleaved"). Staging: coalesced row loads + uint4 LDS writes
// (aligned: 260%4==0; conflict-free). Fragment: 4x ds_read_b32 at immediate
// offsets (+260 words); fg groups offset by 4*260%32 = 16 banks -> exactly
// 2 lanes/bank (free). Grid 1-D, o innermost + bijective XCD swizzle.
// ---------------------------------------------------------------------------
template <bool IN_F32, bool OUT_BF16>
__global__ __launch_bounds__(256) void gemm_cn(
    const u16* __restrict__ Abase, long aStride,
    const void* __restrict__ Bbase, long bStride,
    void* __restrict__ OutBase, long oStride, int nOB) {
  const int nwg = (int)gridDim.x;
  const int wg = ((int)blockIdx.x & 7) * (nwg >> 3) + ((int)blockIdx.x >> 3);
  const int o0 = (wg % nOB) * 64;
  const int rest = wg / nOB;
  const int n0 = (rest & 63) * 256;
  const int b  = rest >> 6;

  const int t = threadIdx.x;
  const int lane = t & 63, wv = t >> 6;
  const int fr = lane & 15, fg = lane >> 4;

  __shared__ u16 As[64 * 64];                 // [o][k] swizzled, 8 KB
  __shared__ __align__(16) u32 Bs[32 * 260];  // k-pair interleaved, 33.3 KB

  const u16* A = Abase + (size_t)b * aStride;

  fx4 acc[4][4];
#pragma unroll
  for (int m = 0; m < 4; ++m)
#pragma unroll
    for (int n = 0; n < 4; ++n) acc[m][n] = (fx4){0.f, 0.f, 0.f, 0.f};

  for (int k0 = 0; k0 < kC; k0 += 64) {
    if (k0) __syncthreads();
    // stage A tile (64 o x 64 k), b128-swizzled (unchanged from proven kernel)
#pragma unroll
    for (int i = 0; i < 2; ++i) {
      int idx = t + i * 256;
      int row = idx >> 3, sl = idx & 7;
      uint4 v = *(const uint4*)(A + (size_t)(o0 + row) * kC + k0 + sl * 8);
      *(uint4*)(As + row * 64 + ((sl ^ (row & 7)) * 8)) = v;
    }
    // stage B tile (64 k x 256 n) -> k-pair interleaved LDS
    if constexpr (IN_F32) {
      const float* Bg = (const float*)Bbase + (size_t)b * bStride;
#pragma unroll
      for (int i = 0; i < 8; ++i) {
        int p = i * 4 + wv;                 // pair 0..31
        int k = k0 + 2 * p;
        const float* s0 = Bg + (size_t)k * kHW + n0 + lane * 4;
        float4 a = *(const float4*)s0;
        float4 c = *(const float4*)(s0 + (size_t)kHW);
        *(uint4*)(&Bs[p * 260 + lane * 4]) = make_uint4(
            pack2(a.x, c.x), pack2(a.y, c.y), pack2(a.z, c.z), pack2(a.w, c.w));
      }
    } else {
      const u16* Bg = (const u16*)Bbase + (size_t)b * bStride;
#pragma unroll
      for (int i = 0; i < 8; ++i) {
        int p = i * 4 + wv;
        int k = k0 + 2 * p;
        const u16* s0 = Bg + (size_t)k * kHW + n0 + lane * 4;
        uint2 a = *(const uint2*)s0;                  // row k  : n0..n3
        uint2 c = *(const uint2*)(s0 + (size_t)kHW);  // row k+1: n0..n3
        u32 w0 = (a.x & 0xffffu) | (c.x << 16);
        u32 w1 = (a.x >> 16)     | (c.x & 0xffff0000u);
        u32 w2 = (a.y & 0xffffu) | (c.y << 16);
        u32 w3 = (a.y >> 16)     | (c.y & 0xffff0000u);
        *(uint4*)(&Bs[p * 260 + lane * 4]) = make_uint4(w0, w1, w2, w3);
      }
    }
    __syncthreads();
#pragma unroll
    for (int ks = 0; ks < 2; ++ks) {
      bfx8 af[4], bf[4];
#pragma unroll
      for (int m = 0; m < 4; ++m) {
        int row = m * 16 + fr;
        af[m] = *(const bfx8*)(As + row * 64 + (((ks * 4 + fg) ^ (row & 7)) * 8));
      }
#pragma unroll
      for (int nf = 0; nf < 4; ++nf) {
        int base = (ks * 16 + fg * 4) * 260 + wv * 64 + nf * 16 + fr;
        union { uint4 u; bfx8 f; } cv;
        cv.u = make_uint4(Bs[base], Bs[base + 260], Bs[base + 520], Bs[base + 780]);
        bf[nf] = cv.f;
      }
#pragma unroll
      for (int m = 0; m < 4; ++m)
#pragma unroll
        for (int n = 0; n < 4; ++n)
          acc[m][n] = __builtin_amdgcn_mfma_f32_16x16x32_bf16(af[m], bf[n], acc[m][n], 0, 0, 0);
    }
  }

  if constexpr (OUT_BF16) {
    u16* O = (u16*)OutBase + (size_t)b * oStride;
#pragma unroll
    for (int m = 0; m < 4; ++m)
#pragma unroll
      for (int n = 0; n < 4; ++n) {
        int col = n0 + wv * 64 + n * 16 + fr;
#pragma unroll
        for (int r = 0; r < 4; ++r)
          O[(size_t)(o0 + m * 16 + fg * 4 + r) * kHW + col] = f2bfu(acc[m][n][r]);
      }
  } else {
    float* O = (float*)OutBase + (size_t)b * oStride;
#pragma unroll
    for (int m = 0; m < 4; ++m)
#pragma unroll
      for (int n = 0; n < 4; ++n) {
        int col = n0 + wv * 64 + n * 16 + fr;
#pragma unroll
        for (int r = 0; r < 4; ++r)
          O[(size_t)(o0 + m * 16 + fg * 4 + r) * kHW + col] = acc[m][n][r];
      }
  }
}

// ---------------------------------------------------------------------------
// K2: depthwise 3x3 'SAME'. 8 output rows x 8 cols per thread, rolling row
// window; halo cols come from neighbor lanes via shfl (no scalar loads).
// Emits per-plane sum-of-squares for q,k channels.
// ---------------------------------------------------------------------------
__device__ __forceinline__ void load_row3(const u16* __restrict__ plane, int hh,
                                          int w8, float v[10]) {
  uint4 m = make_uint4(0u, 0u, 0u, 0u);
  if ((unsigned)hh <= 127u) m = *(const uint4*)(plane + hh * 128 + w8 * 8);
  u32 left  = __shfl_up(m.w >> 16, 1);       // prev lane's col w8*8+7
  u32 right = __shfl_down(m.x & 0xffffu, 1); // next lane's col w8*8+8... wait: its col (w8+1)*8
  v[1] = bfu2f(m.x & 0xffffu); v[2] = bfu2f(m.x >> 16);
  v[3] = bfu2f(m.y & 0xffffu); v[4] = bfu2f(m.y >> 16);
  v[5] = bfu2f(m.z & 0xffffu); v[6] = bfu2f(m.z >> 16);
  v[7] = bfu2f(m.w & 0xffffu); v[8] = bfu2f(m.w >> 16);
  v[0] = (w8 > 0)  ? bfu2f(left)  : 0.f;
  v[9] = (w8 < 15) ? bfu2f(right) : 0.f;
}

__global__ __launch_bounds__(256) void dwconv3x3_v3(
    const u16* __restrict__ in, const float* __restrict__ wdw,
    u16* __restrict__ out, float* __restrict__ ssqp) {
  const int bc = blockIdx.x;            // plane index b*576+ch
  const int ch = bc % kC3;
  const int t = threadIdx.x;
  const int w8 = t & 15;
  const int h0 = (t >> 4) * 8;
  const u16* p = in + (size_t)bc * kHW;
  float wt[9];
#pragma unroll
  for (int j = 0; j < 9; ++j) wt[j] = wdw[ch * 9 + j];

  float v[3][10];
  load_row3(p, h0 - 1, w8, v[0]);
  load_row3(p, h0,     w8, v[1]);
  float ssq = 0.f;
  u16* op = out + (size_t)bc * kHW + h0 * 128 + w8 * 8;
#pragma unroll
  for (int r = 0; r < 8; ++r) {
    load_row3(p, h0 + r + 1, w8, v[(r + 2) % 3]);
    const float* r0 = v[r % 3];
    const float* r1 = v[(r + 1) % 3];
    const float* r2 = v[(r + 2) % 3];
    float o[8];
#pragma unroll
    for (int j = 0; j < 8; ++j) {
      o[j] = wt[0] * r0[j] + wt[1] * r0[j + 1] + wt[2] * r0[j + 2]
           + wt[3] * r1[j] + wt[4] * r1[j + 1] + wt[5] * r1[j + 2]
           + wt[6] * r2[j] + wt[7] * r2[j + 1] + wt[8] * r2[j + 2];
      ssq += o[j] * o[j];
    }
    *(uint4*)(op + r * 128) = make_uint4(pack2(o[0], o[1]), pack2(o[2], o[3]),
                                         pack2(o[4], o[5]), pack2(o[6], o[7]));
  }
  if (ch < 2 * kC) {  // q,k channels: block-uniform branch
#pragma unroll
    for (int d = 1; d < 64; d <<= 1) ssq += __shfl_xor(ssq, d);
    __shared__ float red[4];
    if ((t & 63) == 0) red[t >> 6] = ssq;
    __syncthreads();
    if (t == 0) ssqp[bc] = red[0] + red[1] + red[2] + red[3];
  }
}

// ---------------------------------------------------------------------------
// K3: LDS-staged MFMA split-K of S = q k^T. Block = (chunk of 1024 n, bh).
// ---------------------------------------------------------------------------
__global__ __launch_bounds__(256) void qk_mfma_lds(
    const u16* __restrict__ qkv2, float* __restrict__ Spart) {
  const int chunk = blockIdx.x;   // 0..15
  const int bh = blockIdx.y;      // 0..31
  const int b = bh >> 2, hh = bh & 3;
  const u16* qp = qkv2 + (size_t)(b * kC3 + hh * kHD) * kHW;
  const u16* kp = qp + (size_t)kC * kHW;

  __shared__ u16 smem[24576];     // 48 KB: qs | ks; sred aliases
  u16* qs = smem;
  u16* ks = smem + 12288;
  float* sred = (float*)smem;

  const int t = threadIdx.x;
  const int wv = t >> 6, lane = t & 63;
  const int fr = lane & 15, fg = lane >> 4;

  fx4 acc[3][3];
#pragma unroll
  for (int i = 0; i < 3; ++i)
#pragma unroll
    for (int j = 0; j < 3; ++j) acc[i][j] = (fx4){0.f, 0.f, 0.f, 0.f};

  for (int round = 0; round < 4; ++round) {
    if (round) __syncthreads();
    const int nb = chunk * 1024 + round * 256;
#pragma unroll
    for (int j = 0; j < 6; ++j) {   // 1536 uint4 per operand
      int idx = t + j * 256;
      int c = idx >> 5, sl = idx & 31;
      *(uint4*)(qs + c * 256 + ((sl ^ (c & 31)) * 8)) =
          *(const uint4*)(qp + (size_t)c * kHW + nb + sl * 8);
      *(uint4*)(ks + c * 256 + ((sl ^ (c & 31)) * 8)) =
          *(const uint4*)(kp + (size_t)c * kHW + nb + sl * 8);
    }
    __syncthreads();
#pragma unroll
    for (int s = 0; s < 2; ++s) {
      const int slot = wv * 8 + s * 4 + fg;
      bfx8 aq[3], ak[3];
#pragma unroll
      for (int tt = 0; tt < 3; ++tt) {
        int c = tt * 16 + fr;
        aq[tt] = *(const bfx8*)(qs + c * 256 + ((slot ^ (c & 31)) * 8));
        ak[tt] = *(const bfx8*)(ks + c * 256 + ((slot ^ (c & 31)) * 8));
      }
#pragma unroll
      for (int i = 0; i < 3; ++i)
#pragma unroll
        for (int j = 0; j < 3; ++j)
          acc[i][j] = __builtin_amdgcn_mfma_f32_16x16x32_bf16(aq[i], ak[j], acc[i][j], 0, 0, 0);
    }
  }

  __syncthreads();                 // tile reads done; reuse LDS for reduce
  float* my = sred + wv * 2400;
#pragma unroll
  for (int i = 0; i < 3; ++i)
#pragma unroll
    for (int j = 0; j < 3; ++j)
#pragma unroll
      for (int r = 0; r < 4; ++r)
        my[(i * 16 + fg * 4 + r) * 50 + j * 16 + fr] = acc[i][j][r];
  __syncthreads();
  float* Sp = Spart + ((size_t)chunk * 32 + bh) * (kHD * kHD);
  for (int p = t; p < kHD * kHD; p += 256) {
    int idx = (p / kHD) * 50 + (p % kHD);
    Sp[p] = sred[idx] + sred[2400 + idx] + sred[4800 + idx] + sred[7200 + idx];
  }
}

// ---------------------------------------------------------------------------
// K3b: reduce partials, fold norms (eps=1e-12) + temperature, row softmax.
// ---------------------------------------------------------------------------
__global__ __launch_bounds__(256) void attn_softmax(
    const float* __restrict__ Spart, const float* __restrict__ ssqp,
    const float* __restrict__ temp, float* __restrict__ attn) {
  const int bh = blockIdx.x, b = bh >> 2, hh = bh & 3;
  const int t = threadIdx.x;
  __shared__ float S[kHD * kHD];
  __shared__ float qn[kHD], kinv[kHD];
  for (int p = t; p < kHD * kHD; p += 256) {
    float s = 0.f;
#pragma unroll
    for (int c = 0; c < kSCH; ++c) s += Spart[((size_t)c * 32 + bh) * (kHD * kHD) + p];
    S[p] = s;
  }
  if (t < 48) {
    qn[t] = sqrtf(ssqp[b * kC3 + hh * kHD + t]);
  } else if (t < 96) {
    kinv[t - 48] = 1.f / fmaxf(sqrtf(ssqp[b * kC3 + kC + hh * kHD + (t - 48)]), 1e-12f);
  }
  __syncthreads();
  if (t < 48) {
    const float T = temp[hh];
    const float sqr = T / fmaxf(qn[t], 1e-12f);
    float m = -3.4e38f;
    for (int d = 0; d < kHD; ++d) {
      float v = S[t * kHD + d] * sqr * kinv[d];
      S[t * kHD + d] = v;
      m = fmaxf(m, v);
    }
    float sum = 0.f;
    for (int d = 0; d < kHD; ++d) {
      float e = expf(S[t * kHD + d] - m);
      S[t * kHD + d] = e;
      sum += e;
    }
    const float inv = 1.f / sum;
    float* A = attn + (size_t)bh * (kHD * kHD) + t * kHD;
    for (int d = 0; d < kHD; ++d) A[d] = S[t * kHD + d] * inv;
  }
}

// ---------------------------------------------------------------------------
// K4: M[b][o][j=hh*48+d] = sum_c w_out[o][hh*48+c] * attn[b,hh,c,d]  (bf16)
// ---------------------------------------------------------------------------
__global__ __launch_bounds__(256) void make_m(
    const float* __restrict__ wout, const float* __restrict__ attn, u16* __restrict__ M) {
  int g = blockIdx.x * 256 + threadIdx.x;
  if (g >= kB * kC * kC) return;
  int j = g % kC;
  int o = (g / kC) % kC;
  int b = g / (kC * kC);
  int hh = j / kHD, d = j % kHD;
  const float* A = attn + (size_t)(b * 4 + hh) * (kHD * kHD) + d;
  const float* wo = wout + (size_t)o * kC + hh * kHD;
  float s = 0.f;
#pragma unroll
  for (int c = 0; c < kHD; ++c) s += wo[c] * A[c * kHD];
  M[g] = f2bfu(s);
}

// ---------------------------------------------------------------------------
extern "C" void kernel_launch(void* const* d_in, const int* in_sizes, int n_in,
                              void* d_out, int out_size, void* d_ws, size_t ws_size,
                              hipStream_t stream) {
  const float* x    = (const float*)d_in[0];
  const float* wqkv = (const float*)d_in[1];
  const float* wdw  = (const float*)d_in[2];
  const float* temp = (const float*)d_in[3];
  const float* wout = (const float*)d_in[4];

  size_t off = 0;
  u16* qkv1 = (u16*)((char*)d_ws + off); off += (size_t)kB * kC3 * kHW * 2;  // 151 MB
  u16* qkv2 = (u16*)((char*)d_ws + off); off += (size_t)kB * kC3 * kHW * 2;  // 151 MB
  u16* Wq   = (u16*)((char*)d_ws + off); off += (size_t)kC3 * kC * 2;
  float* ssqp = (float*)((char*)d_ws + off); off += (size_t)kB * kC3 * 4;
  if (off > ws_size) return;  // insufficient workspace -> fail visibly

  // attention scratch aliases qkv1 (dead after dwconv)
  float* Spart = (float*)qkv1;                              // 16*32*2304*4 = 4.7 MB
  float* attnb = Spart + (size_t)kSCH * 32 * kHD * kHD;
  u16*   Mb    = (u16*)(attnb + (size_t)32 * kHD * kHD);

  // P1: weight cast
  cast_f32_bf16<<<dim3((kC3 * kC + 255) / 256), 256, 0, stream>>>(wqkv, Wq, kC3 * kC);
  // K1: qkv1 = Wq @ x (MFMA, x [c][n] f32 consumed directly); grid 4608 (%8==0)
  gemm_cn<true, true><<<dim3((kC3 / 64) * 64 * kB), 256, 0, stream>>>(
      Wq, 0L, (const void*)x, (long)kC * kHW, (void*)qkv1, (long)kC3 * kHW, kC3 / 64);
  // K2: depthwise 3x3 (+ q,k per-plane sumsq)
  dwconv3x3_v3<<<dim3(kB * kC3), 256, 0, stream>>>(qkv1, wdw, qkv2, ssqp);
  // K3: S partials (LDS-staged MFMA)
  qk_mfma_lds<<<dim3(kSCH, 32), 256, 0, stream>>>(qkv2, Spart);
  // K3b: reduce + normalize + softmax
  attn_softmax<<<dim3(32), 256, 0, stream>>>(Spart, ssqp, temp, attnb);
  // K4: M = w_out folded through attn (bf16)
  make_m<<<dim3((kB * kC * kC + 255) / 256), 256, 0, stream>>>(wout, attnb, Mb);
  // K5: out = M @ v (MFMA, v [c][n] bf16 consumed directly); grid 1536 (%8==0)
  gemm_cn<false, false><<<dim3((kC / 64) * 64 * kB), 256, 0, stream>>>(
      Mb, (long)kC * kC, (const void*)(qkv2 + (size_t)2 * kC * kHW),
      (long)kC3 * kHW, d_out, (long)kC * kHW, kC / 64);
}

// Round 8
// 227.151 us; speedup vs baseline: 1.2280x; 1.2280x over previous
//
#include <hip/hip_runtime.h>
#include <hip/hip_bf16.h>

typedef unsigned short u16;
typedef unsigned int u32;

constexpr int kHW  = 16384;   // 128*128
constexpr int kC   = 192;
constexpr int kC3  = 576;
constexpr int kHD  = 48;
constexpr int kB   = 8;
constexpr int kSCH = 16;      // S-partial chunks (1024 n each)

typedef __attribute__((ext_vector_type(8))) short bfx8;  // 8 bf16 in 4 VGPRs
typedef __attribute__((ext_vector_type(4))) float fx4;

__device__ __forceinline__ float bfu2f(u32 u) { return __uint_as_float(u << 16); }
__device__ __forceinline__ u16 f2bfu(float f) {
  u32 x = __float_as_uint(f);
  return (u16)((x + 0x7fffu + ((x >> 16) & 1u)) >> 16);  // RNE
}
__device__ __forceinline__ u32 pack2(float a, float b) {
  union { __hip_bfloat162 h; u32 u; } cv;
  cv.h = __float22bfloat162_rn(make_float2(a, b));  // v_cvt_pk_bf16_f32
  return cv.u;
}

// ---------------------------------------------------------------------------
// P1: f32 -> bf16 cast (for w_qkv)
// ---------------------------------------------------------------------------
__global__ __launch_bounds__(256) void cast_f32_bf16(
    const float* __restrict__ in, u16* __restrict__ out, int n) {
  int i = blockIdx.x * 256 + threadIdx.x;
  if (i < n) out[i] = f2bfu(in[i]);
}

// ---------------------------------------------------------------------------
// K1/K5: MFMA GEMM, B consumed DIRECTLY from [k][n] row-major global layout.
// Out[b][o][n] = sum_k A[b?][o][k] * B[b][k][n], K = 192.
// Block tile 192o x 128n, 512 threads = 8 waves (wave-tile 48o x 64n, 4x2).
// Big o-tile minimizes B re-reads through L2/L3 (round-7 lesson: 64o tile
// pulled 9x201MB=1.8GB through the cache path and was cache-BW-bound).
//   K1: nOB=3 -> 600 MB L2 reads.  K5: nOB=1 -> v read exactly once.
// B LDS layout: k-pair interleaved, element (k,n) at u32 word (k/2)*132+n,
// half (k&1). Staging = coalesced row loads + uint4 writes (conflict-free);
// fragment = 4x ds_read_b32 (+132-word imm offsets), 2 lanes/bank = free
// (proven round 7: SQ_LDS_BANK_CONFLICT = 0). A and B share the exact k-map.
// Grid 1-D, o innermost + bijective XCD swizzle (gridDim %8==0).
// ---------------------------------------------------------------------------
template <bool IN_F32, bool OUT_BF16>
__global__ __launch_bounds__(512, 4) void gemm_cn2(
    const u16* __restrict__ Abase, long aStride,
    const void* __restrict__ Bbase, long bStride,
    void* __restrict__ OutBase, long oStride, int nOB) {
  const int nwg = (int)gridDim.x;
  const int wg = ((int)blockIdx.x & 7) * (nwg >> 3) + ((int)blockIdx.x >> 3);
  const int o0 = (wg % nOB) * 192;
  const int rest = wg / nOB;
  const int n0 = (rest & 127) * 128;
  const int b  = rest >> 7;

  const int t = threadIdx.x;
  const int lane = t & 63, wv = t >> 6;     // 8 waves
  const int wo = wv & 3, wn = wv >> 2;      // wave-grid 4(o) x 2(n)
  const int fr = lane & 15, fg = lane >> 4;

  __shared__ u16 As[192 * 64];                // [o][k] swizzled, 24 KB
  __shared__ __align__(16) u32 Bs[32 * 132];  // k-pair interleaved, 16.9 KB

  const u16* A = Abase + (size_t)b * aStride;

  fx4 acc[3][4];
#pragma unroll
  for (int m = 0; m < 3; ++m)
#pragma unroll
    for (int n = 0; n < 4; ++n) acc[m][n] = (fx4){0.f, 0.f, 0.f, 0.f};

  for (int k0 = 0; k0 < kC; k0 += 64) {
    if (k0) __syncthreads();
    // stage A tile (192 o x 64 k): 1536 uint4 / 512 thr
#pragma unroll
    for (int i = 0; i < 3; ++i) {
      int idx = t + i * 512;
      int row = idx >> 3, sl = idx & 7;
      uint4 v = *(const uint4*)(A + (size_t)(o0 + row) * kC + k0 + sl * 8);
      *(uint4*)(As + row * 64 + ((sl ^ (row & 7)) * 8)) = v;
    }
    // stage B tile (64 k x 128 n) -> k-pair interleaved LDS
    if constexpr (IN_F32) {
      const float* Bg = (const float*)Bbase + (size_t)b * bStride;
#pragma unroll
      for (int i = 0; i < 2; ++i) {
        int slot = t + i * 512;            // 1024 slots: pair p x n-quad
        int p = slot >> 5, nq = slot & 31;
        const float* s0 = Bg + (size_t)(k0 + 2 * p) * kHW + n0 + nq * 4;
        float4 a = *(const float4*)s0;
        float4 c = *(const float4*)(s0 + (size_t)kHW);
        *(uint4*)(&Bs[p * 132 + nq * 4]) = make_uint4(
            pack2(a.x, c.x), pack2(a.y, c.y), pack2(a.z, c.z), pack2(a.w, c.w));
      }
    } else {
      const u16* Bg = (const u16*)Bbase + (size_t)b * bStride;
      int p = t >> 4, n8 = (t & 15) * 8;   // 512 slots: pair p x n-oct
      const u16* s0 = Bg + (size_t)(k0 + 2 * p) * kHW + n0 + n8;
      union { uint4 u; u16 h[8]; } a, c;
      a.u = *(const uint4*)s0;
      c.u = *(const uint4*)(s0 + (size_t)kHW);
      u32 w[8];
#pragma unroll
      for (int j = 0; j < 8; ++j) w[j] = (u32)a.h[j] | ((u32)c.h[j] << 16);
      *(uint4*)(&Bs[p * 132 + n8])     = make_uint4(w[0], w[1], w[2], w[3]);
      *(uint4*)(&Bs[p * 132 + n8 + 4]) = make_uint4(w[4], w[5], w[6], w[7]);
    }
    __syncthreads();
#pragma unroll
    for (int ks = 0; ks < 2; ++ks) {
      bfx8 af[3], bf[4];
#pragma unroll
      for (int m = 0; m < 3; ++m) {
        int row = wo * 48 + m * 16 + fr;
        af[m] = *(const bfx8*)(As + row * 64 + (((ks * 4 + fg) ^ (row & 7)) * 8));
      }
#pragma unroll
      for (int nf = 0; nf < 4; ++nf) {
        int base = (ks * 16 + fg * 4) * 132 + wn * 64 + nf * 16 + fr;
        union { uint4 u; bfx8 f; } cv;
        cv.u = make_uint4(Bs[base], Bs[base + 132], Bs[base + 264], Bs[base + 396]);
        bf[nf] = cv.f;
      }
#pragma unroll
      for (int m = 0; m < 3; ++m)
#pragma unroll
        for (int n = 0; n < 4; ++n)
          acc[m][n] = __builtin_amdgcn_mfma_f32_16x16x32_bf16(af[m], bf[n], acc[m][n], 0, 0, 0);
    }
  }

  if constexpr (OUT_BF16) {
    u16* O = (u16*)OutBase + (size_t)b * oStride;
#pragma unroll
    for (int m = 0; m < 3; ++m)
#pragma unroll
      for (int n = 0; n < 4; ++n) {
        int col = n0 + wn * 64 + n * 16 + fr;
#pragma unroll
        for (int r = 0; r < 4; ++r)
          O[(size_t)(o0 + wo * 48 + m * 16 + fg * 4 + r) * kHW + col] = f2bfu(acc[m][n][r]);
      }
  } else {
    float* O = (float*)OutBase + (size_t)b * oStride;
#pragma unroll
    for (int m = 0; m < 3; ++m)
#pragma unroll
      for (int n = 0; n < 4; ++n) {
        int col = n0 + wn * 64 + n * 16 + fr;
#pragma unroll
        for (int r = 0; r < 4; ++r)
          O[(size_t)(o0 + wo * 48 + m * 16 + fg * 4 + r) * kHW + col] = acc[m][n][r];
      }
  }
}

// ---------------------------------------------------------------------------
// K2: depthwise 3x3 'SAME'. 8 output rows x 8 cols per thread, rolling row
// window; halo cols come from neighbor lanes via shfl (no scalar loads).
// Emits per-plane sum-of-squares for q,k channels.
// ---------------------------------------------------------------------------
__device__ __forceinline__ void load_row3(const u16* __restrict__ plane, int hh,
                                          int w8, float v[10]) {
  uint4 m = make_uint4(0u, 0u, 0u, 0u);
  if ((unsigned)hh <= 127u) m = *(const uint4*)(plane + hh * 128 + w8 * 8);
  u32 left  = __shfl_up(m.w >> 16, 1);        // prev lane's last col
  u32 right = __shfl_down(m.x & 0xffffu, 1);  // next lane's first col
  v[1] = bfu2f(m.x & 0xffffu); v[2] = bfu2f(m.x >> 16);
  v[3] = bfu2f(m.y & 0xffffu); v[4] = bfu2f(m.y >> 16);
  v[5] = bfu2f(m.z & 0xffffu); v[6] = bfu2f(m.z >> 16);
  v[7] = bfu2f(m.w & 0xffffu); v[8] = bfu2f(m.w >> 16);
  v[0] = (w8 > 0)  ? bfu2f(left)  : 0.f;
  v[9] = (w8 < 15) ? bfu2f(right) : 0.f;
}

__global__ __launch_bounds__(256) void dwconv3x3_v3(
    const u16* __restrict__ in, const float* __restrict__ wdw,
    u16* __restrict__ out, float* __restrict__ ssqp) {
  const int bc = blockIdx.x;            // plane index b*576+ch
  const int ch = bc % kC3;
  const int t = threadIdx.x;
  const int w8 = t & 15;
  const int h0 = (t >> 4) * 8;
  const u16* p = in + (size_t)bc * kHW;
  float wt[9];
#pragma unroll
  for (int j = 0; j < 9; ++j) wt[j] = wdw[ch * 9 + j];

  float v[3][10];
  load_row3(p, h0 - 1, w8, v[0]);
  load_row3(p, h0,     w8, v[1]);
  float ssq = 0.f;
  u16* op = out + (size_t)bc * kHW + h0 * 128 + w8 * 8;
#pragma unroll
  for (int r = 0; r < 8; ++r) {
    load_row3(p, h0 + r + 1, w8, v[(r + 2) % 3]);
    const float* r0 = v[r % 3];
    const float* r1 = v[(r + 1) % 3];
    const float* r2 = v[(r + 2) % 3];
    float o[8];
#pragma unroll
    for (int j = 0; j < 8; ++j) {
      o[j] = wt[0] * r0[j] + wt[1] * r0[j + 1] + wt[2] * r0[j + 2]
           + wt[3] * r1[j] + wt[4] * r1[j + 1] + wt[5] * r1[j + 2]
           + wt[6] * r2[j] + wt[7] * r2[j + 1] + wt[8] * r2[j + 2];
      ssq += o[j] * o[j];
    }
    *(uint4*)(op + r * 128) = make_uint4(pack2(o[0], o[1]), pack2(o[2], o[3]),
                                         pack2(o[4], o[5]), pack2(o[6], o[7]));
  }
  if (ch < 2 * kC) {  // q,k channels: block-uniform branch
#pragma unroll
    for (int d = 1; d < 64; d <<= 1) ssq += __shfl_xor(ssq, d);
    __shared__ float red[4];
    if ((t & 63) == 0) red[t >> 6] = ssq;
    __syncthreads();
    if (t == 0) ssqp[bc] = red[0] + red[1] + red[2] + red[3];
  }
}

// ---------------------------------------------------------------------------
// K3: LDS-staged MFMA split-K of S = q k^T. Block = (chunk of 1024 n, bh).
// ---------------------------------------------------------------------------
__global__ __launch_bounds__(256) void qk_mfma_lds(
    const u16* __restrict__ qkv2, float* __restrict__ Spart) {
  const int chunk = blockIdx.x;   // 0..15
  const int bh = blockIdx.y;      // 0..31
  const int b = bh >> 2, hh = bh & 3;
  const u16* qp = qkv2 + (size_t)(b * kC3 + hh * kHD) * kHW;
  const u16* kp = qp + (size_t)kC * kHW;

  __shared__ u16 smem[24576];     // 48 KB: qs | ks; sred aliases
  u16* qs = smem;
  u16* ks = smem + 12288;
  float* sred = (float*)smem;

  const int t = threadIdx.x;
  const int wv = t >> 6, lane = t & 63;
  const int fr = lane & 15, fg = lane >> 4;

  fx4 acc[3][3];
#pragma unroll
  for (int i = 0; i < 3; ++i)
#pragma unroll
    for (int j = 0; j < 3; ++j) acc[i][j] = (fx4){0.f, 0.f, 0.f, 0.f};

  for (int round = 0; round < 4; ++round) {
    if (round) __syncthreads();
    const int nb = chunk * 1024 + round * 256;
#pragma unroll
    for (int j = 0; j < 6; ++j) {   // 1536 uint4 per operand
      int idx = t + j * 256;
      int c = idx >> 5, sl = idx & 31;
      *(uint4*)(qs + c * 256 + ((sl ^ (c & 31)) * 8)) =
          *(const uint4*)(qp + (size_t)c * kHW + nb + sl * 8);
      *(uint4*)(ks + c * 256 + ((sl ^ (c & 31)) * 8)) =
          *(const uint4*)(kp + (size_t)c * kHW + nb + sl * 8);
    }
    __syncthreads();
#pragma unroll
    for (int s = 0; s < 2; ++s) {
      const int slot = wv * 8 + s * 4 + fg;
      bfx8 aq[3], ak[3];
#pragma unroll
      for (int tt = 0; tt < 3; ++tt) {
        int c = tt * 16 + fr;
        aq[tt] = *(const bfx8*)(qs + c * 256 + ((slot ^ (c & 31)) * 8));
        ak[tt] = *(const bfx8*)(ks + c * 256 + ((slot ^ (c & 31)) * 8));
      }
#pragma unroll
      for (int i = 0; i < 3; ++i)
#pragma unroll
        for (int j = 0; j < 3; ++j)
          acc[i][j] = __builtin_amdgcn_mfma_f32_16x16x32_bf16(aq[i], ak[j], acc[i][j], 0, 0, 0);
    }
  }

  __syncthreads();                 // tile reads done; reuse LDS for reduce
  float* my = sred + wv * 2400;
#pragma unroll
  for (int i = 0; i < 3; ++i)
#pragma unroll
    for (int j = 0; j < 3; ++j)
#pragma unroll
      for (int r = 0; r < 4; ++r)
        my[(i * 16 + fg * 4 + r) * 50 + j * 16 + fr] = acc[i][j][r];
  __syncthreads();
  float* Sp = Spart + ((size_t)chunk * 32 + bh) * (kHD * kHD);
  for (int p = t; p < kHD * kHD; p += 256) {
    int idx = (p / kHD) * 50 + (p % kHD);
    Sp[p] = sred[idx] + sred[2400 + idx] + sred[4800 + idx] + sred[7200 + idx];
  }
}

// ---------------------------------------------------------------------------
// K3b: reduce partials, fold norms (eps=1e-12) + temperature, row softmax.
// ---------------------------------------------------------------------------
__global__ __launch_bounds__(256) void attn_softmax(
    const float* __restrict__ Spart, const float* __restrict__ ssqp,
    const float* __restrict__ temp, float* __restrict__ attn) {
  const int bh = blockIdx.x, b = bh >> 2, hh = bh & 3;
  const int t = threadIdx.x;
  __shared__ float S[kHD * kHD];
  __shared__ float qn[kHD], kinv[kHD];
  for (int p = t; p < kHD * kHD; p += 256) {
    float s = 0.f;
#pragma unroll
    for (int c = 0; c < kSCH; ++c) s += Spart[((size_t)c * 32 + bh) * (kHD * kHD) + p];
    S[p] = s;
  }
  if (t < 48) {
    qn[t] = sqrtf(ssqp[b * kC3 + hh * kHD + t]);
  } else if (t < 96) {
    kinv[t - 48] = 1.f / fmaxf(sqrtf(ssqp[b * kC3 + kC + hh * kHD + (t - 48)]), 1e-12f);
  }
  __syncthreads();
  if (t < 48) {
    const float T = temp[hh];
    const float sqr = T / fmaxf(qn[t], 1e-12f);
    float m = -3.4e38f;
    for (int d = 0; d < kHD; ++d) {
      float v = S[t * kHD + d] * sqr * kinv[d];
      S[t * kHD + d] = v;
      m = fmaxf(m, v);
    }
    float sum = 0.f;
    for (int d = 0; d < kHD; ++d) {
      float e = expf(S[t * kHD + d] - m);
      S[t * kHD + d] = e;
      sum += e;
    }
    const float inv = 1.f / sum;
    float* A = attn + (size_t)bh * (kHD * kHD) + t * kHD;
    for (int d = 0; d < kHD; ++d) A[d] = S[t * kHD + d] * inv;
  }
}

// ---------------------------------------------------------------------------
// K4: M[b][o][j=hh*48+d] = sum_c w_out[o][hh*48+c] * attn[b,hh,c,d]  (bf16)
// ---------------------------------------------------------------------------
__global__ __launch_bounds__(256) void make_m(
    const float* __restrict__ wout, const float* __restrict__ attn, u16* __restrict__ M) {
  int g = blockIdx.x * 256 + threadIdx.x;
  if (g >= kB * kC * kC) return;
  int j = g % kC;
  int o = (g / kC) % kC;
  int b = g / (kC * kC);
  int hh = j / kHD, d = j % kHD;
  const float* A = attn + (size_t)(b * 4 + hh) * (kHD * kHD) + d;
  const float* wo = wout + (size_t)o * kC + hh * kHD;
  float s = 0.f;
#pragma unroll
  for (int c = 0; c < kHD; ++c) s += wo[c] * A[c * kHD];
  M[g] = f2bfu(s);
}

// ---------------------------------------------------------------------------
extern "C" void kernel_launch(void* const* d_in, const int* in_sizes, int n_in,
                              void* d_out, int out_size, void* d_ws, size_t ws_size,
                              hipStream_t stream) {
  const float* x    = (const float*)d_in[0];
  const float* wqkv = (const float*)d_in[1];
  const float* wdw  = (const float*)d_in[2];
  const float* temp = (const float*)d_in[3];
  const float* wout = (const float*)d_in[4];

  size_t off = 0;
  u16* qkv1 = (u16*)((char*)d_ws + off); off += (size_t)kB * kC3 * kHW * 2;  // 151 MB
  u16* qkv2 = (u16*)((char*)d_ws + off); off += (size_t)kB * kC3 * kHW * 2;  // 151 MB
  u16* Wq   = (u16*)((char*)d_ws + off); off += (size_t)kC3 * kC * 2;
  float* ssqp = (float*)((char*)d_ws + off); off += (size_t)kB * kC3 * 4;
  if (off > ws_size) return;  // insufficient workspace -> fail visibly

  // attention scratch aliases qkv1 (dead after dwconv)
  float* Spart = (float*)qkv1;                              // 16*32*2304*4 = 4.7 MB
  float* attnb = Spart + (size_t)kSCH * 32 * kHD * kHD;
  u16*   Mb    = (u16*)(attnb + (size_t)32 * kHD * kHD);

  // P1: weight cast
  cast_f32_bf16<<<dim3((kC3 * kC + 255) / 256), 256, 0, stream>>>(wqkv, Wq, kC3 * kC);
  // K1: qkv1 = Wq @ x (MFMA, x [c][n] f32 direct); grid 3*128*8 = 3072 (%8==0)
  gemm_cn2<true, true><<<dim3(3 * 128 * kB), 512, 0, stream>>>(
      Wq, 0L, (const void*)x, (long)kC * kHW, (void*)qkv1, (long)kC3 * kHW, 3);
  // K2: depthwise 3x3 (+ q,k per-plane sumsq)
  dwconv3x3_v3<<<dim3(kB * kC3), 256, 0, stream>>>(qkv1, wdw, qkv2, ssqp);
  // K3: S partials (LDS-staged MFMA)
  qk_mfma_lds<<<dim3(kSCH, 32), 256, 0, stream>>>(qkv2, Spart);
  // K3b: reduce + normalize + softmax
  attn_softmax<<<dim3(32), 256, 0, stream>>>(Spart, ssqp, temp, attnb);
  // K4: M = w_out folded through attn (bf16)
  make_m<<<dim3((kB * kC * kC + 255) / 256), 256, 0, stream>>>(wout, attnb, Mb);
  // K5: out = M @ v (MFMA, v [c][n] bf16 direct, v read once); grid 1024 (%8==0)
  gemm_cn2<false, false><<<dim3(1 * 128 * kB), 512, 0, stream>>>(
      Mb, (long)kC * kC, (const void*)(qkv2 + (size_t)2 * kC * kHW),
      (long)kC3 * kHW, d_out, (long)kC * kHW, 1);
}